// Round 6
// baseline (234.681 us; speedup 1.0000x reference)
//
#include <hip/hip_runtime.h>
#include <hip/hip_bf16.h>
#include <stdint.h>

#define N_PTS   8192
#define D       256
#define N_E     8192
#define BETA    0.25f
#define EPS_1   1.0000001f   // 1 + 1e-7 (rounds to 1+ulp in f32, same as jnp)

typedef unsigned long long u64;
typedef __attribute__((ext_vector_type(8)))  short bf16x8;   // 8 bf16 = 4 VGPR
typedef __attribute__((ext_vector_type(8)))  short short8;
typedef __attribute__((ext_vector_type(16))) float f32x16;

// ---- workspace layout (bytes) ----
// Fragment-linear bf16 arrays for 32x32x16 MFMA: element (p,k) of an
// 8192x256 matrix lives at
//   fi = (p>>5)*16 + (k>>4);  l = (p&31) + 32*((k&15)>>3);  j = k&7
//   idx = fi*512 + l*8 + j
// Each 32x16 MFMA fragment is a contiguous 1KB block in lane-major order:
// global_load_lds(uniform base + lane*16) and ds_read_b128(lane*16) are both
// perfectly linear -> zero bank conflicts (same scheme verified R3/R4: 0).
#define WS_KEYS   0
#define WS_COUNTS (N_PTS * 8)                    // 64 KB
#define WS_LOSS   (WS_COUNTS + N_E * 4)          // +32 KB
#define WS_AHI    (1 << 20)                      // 1 MB-aligned
#define WS_ALO    (WS_AHI + N_PTS * D * 2)
#define WS_BHI    (WS_ALO + N_PTS * D * 2)
#define WS_BLO    (WS_BHI + N_E * D * 2)         // total ~17 MB

__device__ __forceinline__ short f2bf(float x) {
    __hip_bfloat16 h = __float2bfloat16(x);      // RTN-even
    return *reinterpret_cast<short*>(&h);
}
__device__ __forceinline__ float bf2f(short s) {
    __hip_bfloat16 h = *reinterpret_cast<__hip_bfloat16*>(&s);
    return __bfloat162float(h);
}

#define GLOAD16(gp, lp) __builtin_amdgcn_global_load_lds(                      \
    (const __attribute__((address_space(1))) void*)(gp),                       \
    (__attribute__((address_space(3))) void*)(lp), 16, 0, 0)

// ------- init + split f32 -> bf16 hi/lo, fragment-linear (32x16 frags) ------
__global__ __launch_bounds__(256) void k_prep(
    const float* __restrict__ u, const float* __restrict__ cb,
    short* __restrict__ Ahi, short* __restrict__ Alo,
    short* __restrict__ Bhi, short* __restrict__ Blo,
    u64* __restrict__ keys, float* __restrict__ counts,
    double* __restrict__ loss_sum)
{
    const int tid = blockIdx.x * 256 + threadIdx.x;   // 0 .. 262143
    if (tid < N_E)   counts[tid] = 0.f;
    if (tid < N_PTS) keys[tid] = ~0ULL;
    if (tid == 0)    *loss_sum = 0.0;

    const int fi = tid >> 6;             // fragment index (p>>5)*16 + (k>>4)
    const int l  = tid & 63;
    const int p  = (fi >> 4) * 32 + (l & 31);
    const int k  = (fi & 15) * 16 + (l >> 5) * 8;
    const size_t gin  = (size_t)p * D + k;
    const size_t gout = (size_t)tid * 8;

    float v[8];
    short8 h8, l8;

    *(float4*)&v[0] = *(const float4*)&u[gin];
    *(float4*)&v[4] = *(const float4*)&u[gin + 4];
    if (k == 0) v[0] = -v[0];            // Minkowski sign fold on time comp
    #pragma unroll
    for (int j = 0; j < 8; ++j) {
        h8[j] = f2bf(v[j]);
        l8[j] = f2bf(v[j] - bf2f(h8[j]));
    }
    *(short8*)&Ahi[gout] = h8;
    *(short8*)&Alo[gout] = l8;

    *(float4*)&v[0] = *(const float4*)&cb[gin];
    *(float4*)&v[4] = *(const float4*)&cb[gin + 4];
    #pragma unroll
    for (int j = 0; j < 8; ++j) {
        h8[j] = f2bf(v[j]);
        l8[j] = f2bf(v[j] - bf2f(h8[j]));
    }
    *(short8*)&Bhi[gout] = h8;
    *(short8*)&Blo[gout] = l8;
}

// ---------------- MFMA argmin: C = A~ . B^T, per-row argmin, no C write ------
// split-bf16: a.b = ahi.bhi + ahi.blo + alo.bhi  (err ~2^-18 rel, safe margin)
// 128x128 tile, 4 waves (2x2 of 64x64), 32x32x16 MFMA, double-buffered 64KB
// LDS -> 2 blocks/CU (cross-block TLP hides the end-of-step drain: R5 lesson),
// prefetch issued BEFORE compute so loads fly under the 24-MFMA phase (T3/T14).
#define BMM 128
#define BNN 128
#define NKS 8                // K-steps of 32 (= 2 fragment-columns each)

__global__ __launch_bounds__(256, 2) void k_argmin_mfma(
    const short* __restrict__ Ahi, const short* __restrict__ Alo,
    const short* __restrict__ Bhi, const short* __restrict__ Blo,
    u64* __restrict__ keys)
{
    __shared__ short sm[2][4][8 * 512];  // [dbuf][Ahi,Alo,Bhi,Blo][8KB] = 64 KB

    const int t   = threadIdx.x;
    const int w   = t >> 6;              // wave 0..3
    const int l   = t & 63;
    // natural order (R4-verified locality: FETCH 37 MB, L2-resident panels)
    const int rb  = blockIdx.x >> 6;     // 64 row-panels (points)
    const int cbk = blockIdx.x & 63;     // 64 col-panels (codes)
    const int r0  = rb * BMM, c0 = cbk * BNN;
    const int wr  = w >> 1, wc = w & 1;  // 2x2 wave grid, 64x64 each

    // staging role: wave w stages array w (8 fragments of 1KB per K-step)
    const short* gsrc = (w == 0) ? Ahi : (w == 1) ? Alo : (w == 2) ? Bhi : Blo;
    const int eb = ((w < 2) ? rb : cbk) * 4;   // entity-fragment base

    f32x16 acc[2][2];
    #pragma unroll
    for (int i = 0; i < 2; ++i)
        #pragma unroll
        for (int j = 0; j < 2; ++j)
            #pragma unroll
            for (int r = 0; r < 16; ++r) acc[i][j][r] = 0.f;

    // prologue: stage K-tile 0 into buf 0   (frag (rf,kf) -> slot rf*2+kf)
    #pragma unroll
    for (int i = 0; i < 8; ++i)
        GLOAD16(gsrc + ((size_t)(eb + (i >> 1)) * 16 + (i & 1)) * 512 + l * 8,
                &sm[0][w][i * 512]);
    __syncthreads();                     // tile 0 resident for all waves

    for (int kk = 0; kk < NKS; ++kk) {
        const int c = kk & 1;
        // issue next tile's loads FIRST: they fly under this step's MFMAs.
        // buf[c^1] was last read in step kk-1; the barrier at kk-1's end
        // proves every wave is done with it.
        if (kk + 1 < NKS) {
            #pragma unroll
            for (int i = 0; i < 8; ++i)
                GLOAD16(gsrc + ((size_t)(eb + (i >> 1)) * 16 +
                                (kk + 1) * 2 + (i & 1)) * 512 + l * 8,
                        &sm[c ^ 1][w][i * 512]);
        }

        bf16x8 ah[2][2], al[2][2], bh[2][2], bl[2][2];  // [frag][kf]
        #pragma unroll
        for (int m = 0; m < 2; ++m)
            #pragma unroll
            for (int kf = 0; kf < 2; ++kf) {
                ah[m][kf] = *(const bf16x8*)&sm[c][0][((wr*2+m)*2+kf)*512 + l*8];
                al[m][kf] = *(const bf16x8*)&sm[c][1][((wr*2+m)*2+kf)*512 + l*8];
                bh[m][kf] = *(const bf16x8*)&sm[c][2][((wc*2+m)*2+kf)*512 + l*8];
                bl[m][kf] = *(const bf16x8*)&sm[c][3][((wc*2+m)*2+kf)*512 + l*8];
            }
        __builtin_amdgcn_s_setprio(1);
        #pragma unroll
        for (int kf = 0; kf < 2; ++kf)
            #pragma unroll
            for (int m = 0; m < 2; ++m)
                #pragma unroll
                for (int n = 0; n < 2; ++n) {
                    acc[m][n] = __builtin_amdgcn_mfma_f32_32x32x16_bf16(
                        ah[m][kf], bh[n][kf], acc[m][n], 0, 0, 0);
                    acc[m][n] = __builtin_amdgcn_mfma_f32_32x32x16_bf16(
                        ah[m][kf], bl[n][kf], acc[m][n], 0, 0, 0);
                    acc[m][n] = __builtin_amdgcn_mfma_f32_32x32x16_bf16(
                        al[m][kf], bh[n][kf], acc[m][n], 0, 0, 0);
                }
        __builtin_amdgcn_s_setprio(0);
        // drain this step's prefetch (had the whole MFMA phase to fly) and
        // release buf[c] for rewrite; co-resident block hides the wait.
        __syncthreads();
    }

    // epilogue: per-row argmin over this block's 128 codes, then atomicMin
    // 32x32 C/D layout (m74/m101-verified):
    //   col = lane&31, row = (reg&3) + 8*(reg>>2) + 4*(lane>>5)
    const int ch = l & 31;               // column within 32-frag
    #pragma unroll
    for (int m = 0; m < 2; ++m) {
        #pragma unroll
        for (int r = 0; r < 16; ++r) {
            u64 km = ~0ULL;
            #pragma unroll
            for (int n = 0; n < 2; ++n) {
                float mm = fmaxf(-acc[m][n][r], EPS_1);    // m >= 1 > 0
                unsigned code = (unsigned)(c0 + wc * 64 + n * 32 + ch);
                u64 key = ((u64)__float_as_uint(mm) << 32) | code;
                km = key < km ? key : km;
            }
            #pragma unroll
            for (int s = 16; s >= 1; s >>= 1) {            // 32-lane halves
                u64 o = __shfl_xor(km, s);
                km = o < km ? o : km;
            }
            if (ch == 0) {
                const int row = r0 + wr * 64 + m * 32 +
                                (r & 3) + 8 * (r >> 2) + 4 * (l >> 5);
                atomicMin(&keys[row], km);
            }
        }
    }
}

// ---------------- gather z_q, per-pair f32 distance, histogram ----------------
__global__ __launch_bounds__(256) void k_gather(
    const float* __restrict__ u, const float* __restrict__ cb,
    const u64* __restrict__ keys, float* __restrict__ out,
    float* __restrict__ counts, double* __restrict__ loss_sum)
{
    __shared__ float sred[4];
    const int t    = threadIdx.x;
    const int w    = t >> 6;
    const int row  = blockIdx.x * 4 + w;
    const int lane = t & 63;
    const u64 key  = keys[row];
    const int idx  = (int)(unsigned)(key & 0xffffffffULL);

    float* zq = out + 1;
    float4 uv = *(const float4*)&u[(size_t)row * D + lane * 4];
    float4 cv = *(const float4*)&cb[(size_t)idx * D + lane * 4];
    if (lane == 0) uv.x = -uv.x;                  // Lorentzian sign
    float partial = uv.x * cv.x + uv.y * cv.y + uv.z * cv.z + uv.w * cv.w;
    *(float4*)&zq[(size_t)row * D + lane * 4] = cv;

    #pragma unroll
    for (int s = 32; s >= 1; s >>= 1)
        partial += __shfl_xor(partial, s);

    if (lane == 0) {
        float m = fmaxf(-partial, EPS_1);
        sred[w] = acoshf(m);
        atomicAdd(&counts[idx], 1.f);             // scattered: low contention
    }
    __syncthreads();
    if (t == 0)                                   // 1 f64 atomic per block
        atomicAdd(loss_sum, (double)(sred[0] + sred[1] + sred[2] + sred[3]));
}

// ---------------- scalars: loss, perplexity, entropy, e_mean -----------------
__global__ __launch_bounds__(256) void k_final(
    const float* __restrict__ counts, const double* __restrict__ loss_sum,
    float* __restrict__ out)
{
    __shared__ float red[256];
    const int t = threadIdx.x;
    const int OFF_P = 1 + N_PTS * D;
    float ent = 0.f;
    for (int i = t; i < N_E; i += 256) {
        float e = counts[i] * (1.0f / N_PTS);
        out[OFF_P + 2 + i] = e;
        ent -= e * logf(e + 1e-10f);
    }
    red[t] = ent;
    __syncthreads();
    for (int s = 128; s > 0; s >>= 1) {
        if (t < s) red[t] += red[t + s];
        __syncthreads();
    }
    if (t == 0) {
        float entropy = red[0];
        out[0]         = (1.0f + BETA) * (float)(*loss_sum / (double)N_PTS);
        out[OFF_P]     = expf(entropy);
        out[OFF_P + 1] = entropy;
    }
}

// ---------------- launch ----------------
extern "C" void kernel_launch(void* const* d_in, const int* in_sizes, int n_in,
                              void* d_out, int out_size, void* d_ws, size_t ws_size,
                              hipStream_t stream)
{
    const float* u  = (const float*)d_in[0];
    const float* cb = (const float*)d_in[1];
    float* out = (float*)d_out;
    char* ws = (char*)d_ws;

    u64*    keys     = (u64*)(ws + WS_KEYS);
    float*  counts   = (float*)(ws + WS_COUNTS);
    double* loss_sum = (double*)(ws + WS_LOSS);
    short*  Ahi = (short*)(ws + WS_AHI);
    short*  Alo = (short*)(ws + WS_ALO);
    short*  Bhi = (short*)(ws + WS_BHI);
    short*  Blo = (short*)(ws + WS_BLO);

    k_prep<<<N_PTS * D / 8 / 256, 256, 0, stream>>>(u, cb, Ahi, Alo, Bhi, Blo,
                                                    keys, counts, loss_sum);
    k_argmin_mfma<<<(N_PTS / BMM) * (N_E / BNN), 256, 0, stream>>>(
        Ahi, Alo, Bhi, Blo, keys);
    k_gather<<<N_PTS / 4, 256, 0, stream>>>(u, cb, keys, out, counts, loss_sum);
    k_final<<<1, 256, 0, stream>>>(counts, loss_sum, out);
}